// Round 1
// baseline (102.047 us; speedup 1.0000x reference)
//
#include <hip/hip_runtime.h>

#define H 1024
#define W 2048
#define HW (H * W)
#define C 19

__device__ __forceinline__ float dev_log19() { return 2.9444389791664403f; }
#define EPS 1e-6f

// ---------------- K1: softmax entropy + argmax ----------------
__global__ __launch_bounds__(256) void k1_entropy_argmax(
    const float* __restrict__ logit,
    float* __restrict__ entropy,
    unsigned char* __restrict__ predict) {
    int p = blockIdx.x * 256 + threadIdx.x;
    float v[C];
    float m;
    int am = 0;
    v[0] = logit[p];
    m = v[0];
#pragma unroll
    for (int c = 1; c < C; c++) {
        v[c] = logit[c * HW + p];
        if (v[c] > m) { m = v[c]; am = c; }
    }
    float S = 0.f, T = 0.f;
#pragma unroll
    for (int c = 0; c < C; c++) {
        float d = v[c] - m;
        float e = __expf(d);
        S += e;
        T += d * e;
    }
    // H = log S - sum(p*(x-m)); differs from log(p+eps) form by ~1e-5 (<< tol)
    float ent = (__logf(S) - T / S) / dev_log19();
    entropy[p] = ent;
    predict[p] = (unsigned char)am;
}

// ---------------- K2: vertical 33-tap sliding box ----------------
#define CH 16
__global__ __launch_bounds__(256) void k2_vertical(
    const float* __restrict__ entropy,
    const unsigned char* __restrict__ predict,
    float* __restrict__ ventropy,
    unsigned int* __restrict__ vcnt) {  // planar [5][H][W], u8x4 SWAR words
    int x = blockIdx.x * 256 + threadIdx.x;
    int y0 = blockIdx.y * CH;
    unsigned int w[5] = {0u, 0u, 0u, 0u, 0u};
    float es = 0.f;
    // warm-up: window for y0 is rows [y0-16, y0+16]
    for (int yy = y0 - 16; yy <= y0 + 16; yy++) {
        if (yy >= 0 && yy < H) {
            int q = yy * W + x;
            unsigned int c = predict[q];
            unsigned int bit = 1u << ((c & 3u) * 8u);
            unsigned int wi = c >> 2;
#pragma unroll
            for (int k = 0; k < 5; k++) w[k] += (wi == (unsigned)k) ? bit : 0u;
            es += entropy[q];
        }
    }
    for (int y = y0; y < y0 + CH; y++) {
        int q = y * W + x;
        ventropy[q] = es;
#pragma unroll
        for (int k = 0; k < 5; k++) vcnt[k * HW + q] = w[k];
        // slide window [y-16, y+16] -> [y-15, y+17]
        int ya = y + 17, yr = y - 16;
        if (ya < H) {
            int qa = ya * W + x;
            unsigned int c = predict[qa];
            unsigned int bit = 1u << ((c & 3u) * 8u);
            unsigned int wi = c >> 2;
#pragma unroll
            for (int k = 0; k < 5; k++) w[k] += (wi == (unsigned)k) ? bit : 0u;
            es += entropy[qa];
        }
        if (yr >= 0) {
            int qr = yr * W + x;
            unsigned int c = predict[qr];
            unsigned int bit = 1u << ((c & 3u) * 8u);
            unsigned int wi = c >> 2;
#pragma unroll
            for (int k = 0; k < 5; k++) w[k] -= (wi == (unsigned)k) ? bit : 0u;
            es -= entropy[qr];
        }
    }
}

// ---------------- K3: horizontal 33-tap + impurity/score ----------------
#define PPT 8  // 256 threads * 8 px = 2048 = W
__global__ __launch_bounds__(256) void k3_horizontal(
    const float* __restrict__ ventropy,
    const unsigned int* __restrict__ vcnt,
    float* __restrict__ out_score,
    float* __restrict__ out_imp,
    float* __restrict__ out_unc) {
    __shared__ unsigned int lcnt[(W + 32) * 5];  // 41600 B
    __shared__ float lent[W + 32];               // 8320 B
    int y = blockIdx.x;
    int tid = threadIdx.x;
    // cooperative coalesced load; i = col + 16, zero-pad OOB
    for (int i = tid; i < W + 32; i += 256) {
        int col = i - 16;
        if (col >= 0 && col < W) {
            int q = y * W + col;
#pragma unroll
            for (int k = 0; k < 5; k++) lcnt[i * 5 + k] = vcnt[k * HW + q];
            lent[i] = ventropy[q];
        } else {
#pragma unroll
            for (int k = 0; k < 5; k++) lcnt[i * 5 + k] = 0u;
            lent[i] = 0.f;
        }
    }
    __syncthreads();

    int x0 = tid * PPT;
    // u16x2 SWAR accumulators: acc[2k] lanes = classes (4k, 4k+2), acc[2k+1] = (4k+1, 4k+3)
    unsigned int acc[10];
#pragma unroll
    for (int k = 0; k < 10; k++) acc[k] = 0u;
    float es = 0.f;
    // warm-up: window for x0 -> LDS indices [x0, x0+32]
    for (int i = x0; i < x0 + 33; i++) {
#pragma unroll
        for (int k = 0; k < 5; k++) {
            unsigned int wv = lcnt[i * 5 + k];
            acc[2 * k] += wv & 0x00FF00FFu;
            acc[2 * k + 1] += (wv >> 8) & 0x00FF00FFu;
        }
        es += lent[i];
    }
    int rows = min(y + 16, H - 1) - max(y - 16, 0) + 1;
#pragma unroll
    for (int s = 0; s < PPT; s++) {
        int x = x0 + s;
        int cols = min(x + 16, W - 1) - max(x - 16, 0) + 1;
        float inv = 1.0f / (float)(rows * cols);
        float imp = 0.f;
#pragma unroll
        for (int k = 0; k < 5; k++) {
            unsigned int a = acc[2 * k], b = acc[2 * k + 1];
            float d0 = (float)(a & 0xFFFFu) * inv;
            float d1 = (float)(b & 0xFFFFu) * inv;
            float d2 = (float)(a >> 16) * inv;
            imp += d0 * __logf(d0 + EPS);
            imp += d1 * __logf(d1 + EPS);
            imp += d2 * __logf(d2 + EPS);
            if (k < 4) {  // class 4k+3 (k==4 would be pad class 19)
                float d3 = (float)(b >> 16) * inv;
                imp += d3 * __logf(d3 + EPS);
            }
        }
        imp = -imp / dev_log19();
        float unc = es * inv;
        int q = y * W + x;
        out_score[q] = imp * unc;
        out_imp[q] = imp;
        out_unc[q] = unc;
        if (s < PPT - 1) {
            // slide [x, x+32] -> [x+1, x+33]
#pragma unroll
            for (int k = 0; k < 5; k++) {
                unsigned int wa = lcnt[(x + 33) * 5 + k];
                unsigned int wr = lcnt[x * 5 + k];
                acc[2 * k] += wa & 0x00FF00FFu;
                acc[2 * k] -= wr & 0x00FF00FFu;
                acc[2 * k + 1] += (wa >> 8) & 0x00FF00FFu;
                acc[2 * k + 1] -= (wr >> 8) & 0x00FF00FFu;
            }
            es += lent[x + 33] - lent[x];
        }
    }
}

extern "C" void kernel_launch(void* const* d_in, const int* in_sizes, int n_in,
                              void* d_out, int out_size, void* d_ws, size_t ws_size,
                              hipStream_t stream) {
    const float* logit = (const float*)d_in[0];
    float* out = (float*)d_out;
    char* ws = (char*)d_ws;

    float* entropy = (float*)ws;                          // HW*4 = 8 MB
    float* ventropy = (float*)(ws + (size_t)HW * 4);      // HW*4 = 8 MB
    unsigned char* predict = (unsigned char*)(ws + (size_t)HW * 8);  // HW = 2 MB
    unsigned int* vcnt = (unsigned int*)(ws + (size_t)HW * 9);       // HW*20 = 42 MB

    k1_entropy_argmax<<<HW / 256, 256, 0, stream>>>(logit, entropy, predict);
    k2_vertical<<<dim3(W / 256, H / CH), 256, 0, stream>>>(entropy, predict, ventropy, vcnt);
    k3_horizontal<<<H, 256, 0, stream>>>(ventropy, vcnt, out, out + HW, out + 2 * HW);
}